// Round 1
// baseline (331.321 us; speedup 1.0000x reference)
//
#include <hip/hip_runtime.h>

#define NSTEPS 30
#define DIM 192
static constexpr int DHW = DIM * DIM * DIM;

// Tiny pre-kernel: Gauss-Jordan 4x4 inverse (double, partial pivoting) -> d_ws
__global__ void invert4x4_kernel(const float* __restrict__ aff,
                                 float* __restrict__ out, int B) {
    int b = blockIdx.x * blockDim.x + threadIdx.x;
    if (b >= B) return;
    double m[4][8];
    for (int r = 0; r < 4; r++) {
        for (int c = 0; c < 4; c++) {
            m[r][c] = (double)aff[b * 16 + r * 4 + c];
            m[r][c + 4] = (r == c) ? 1.0 : 0.0;
        }
    }
    for (int col = 0; col < 4; col++) {
        int piv = col;
        double best = fabs(m[col][col]);
        for (int r = col + 1; r < 4; r++) {
            double a = fabs(m[r][col]);
            if (a > best) { best = a; piv = r; }
        }
        if (piv != col) {
            for (int c = 0; c < 8; c++) {
                double t = m[col][c]; m[col][c] = m[piv][c]; m[piv][c] = t;
            }
        }
        double inv = 1.0 / m[col][col];
        for (int c = 0; c < 8; c++) m[col][c] *= inv;
        for (int r = 0; r < 4; r++) {
            if (r == col) continue;
            double f = m[r][col];
            if (f != 0.0)
                for (int c = 0; c < 8; c++) m[r][c] -= f * m[col][c];
        }
    }
    for (int r = 0; r < 4; r++)
        for (int c = 0; c < 4; c++)
            out[b * 16 + r * 4 + c] = (float)m[r][c + 4];
}

__global__ __launch_bounds__(256) void deform_kernel(
    const float* __restrict__ verts,
    const float* __restrict__ affine,
    const float* __restrict__ flow,
    const float* __restrict__ invaff,
    float* __restrict__ out_pred,
    float* __restrict__ out_flow,
    int N, int B) {
    int idx = blockIdx.x * blockDim.x + threadIdx.x;
    if (idx >= B * N) return;
    int b = idx / N;
    int n = idx - b * N;

    // affine transform: pred0 = A[0:3,:] @ [v,1]
    const float* A = affine + b * 16;
    const float* v = verts + ((size_t)b * N + n) * 3;
    float vx = v[0], vy = v[1], vz = v[2];
    float x = A[0] * vx + A[1] * vy + A[2]  * vz + A[3];
    float y = A[4] * vx + A[5] * vy + A[6]  * vz + A[7];
    float z = A[8] * vx + A[9] * vy + A[10] * vz + A[11];
    const float px = x, py = y, pz = z;

    const float* F = flow + (size_t)b * 3 * DHW;
    const float scale = (float)(1.0 / NSTEPS);  // matches jnp flow * (1/num_steps)

    float cc[3][8];   // cached (pre-scaled) corner values for current cell
    int key = -1;     // cached cell id

    for (int s = 0; s < NSTEPS; s++) {
        // border clamp (padding_mode='border', align_corners=True equivalent)
        float pd = fminf(fmaxf(x, 0.0f), (float)(DIM - 1));
        float ph = fminf(fmaxf(y, 0.0f), (float)(DIM - 1));
        float pw = fminf(fmaxf(z, 0.0f), (float)(DIM - 1));
        float fd0 = floorf(pd), fh0 = floorf(ph), fw0 = floorf(pw);
        int d0 = (int)fd0, h0 = (int)fh0, w0 = (int)fw0;
        float fd = pd - fd0, fh = ph - fh0, fw = pw - fw0;

        int k = (d0 * DIM + h0) * DIM + w0;
        if (k != key) {
            key = k;
            int d1 = min(d0 + 1, DIM - 1);
            int h1 = min(h0 + 1, DIM - 1);
            int w1 = min(w0 + 1, DIM - 1);
            int r00 = (d0 * DIM + h0) * DIM;
            int r01 = (d0 * DIM + h1) * DIM;
            int r10 = (d1 * DIM + h0) * DIM;
            int r11 = (d1 * DIM + h1) * DIM;
#pragma unroll
            for (int c = 0; c < 3; c++) {
                const float* Fc = F + (size_t)c * DHW;
                cc[c][0] = Fc[r00 + w0] * scale;
                cc[c][1] = Fc[r00 + w1] * scale;
                cc[c][2] = Fc[r01 + w0] * scale;
                cc[c][3] = Fc[r01 + w1] * scale;
                cc[c][4] = Fc[r10 + w0] * scale;
                cc[c][5] = Fc[r10 + w1] * scale;
                cc[c][6] = Fc[r11 + w0] * scale;
                cc[c][7] = Fc[r11 + w1] * scale;
            }
        }

        float omfw = 1.0f - fw, omfh = 1.0f - fh, omfd = 1.0f - fd;
        float vals[3];
#pragma unroll
        for (int c = 0; c < 3; c++) {
            float c00 = cc[c][0] * omfw + cc[c][1] * fw;
            float c01 = cc[c][2] * omfw + cc[c][3] * fw;
            float c10 = cc[c][4] * omfw + cc[c][5] * fw;
            float c11 = cc[c][6] * omfw + cc[c][7] * fw;
            float c0 = c00 * omfh + c01 * fh;
            float c1 = c10 * omfh + c11 * fh;
            vals[c] = c0 * omfd + c1 * fd;
        }
        x += vals[0];
        y += vals[1];
        z += vals[2];
    }

    // flow_int = aux - pred0, laid out (B,3,N)
    float fx = x - px, fy = y - py, fz = z - pz;

    // inverse affine on integrated position
    const float* Ai = invaff + b * 16;
    float ox = Ai[0] * x + Ai[1] * y + Ai[2]  * z + Ai[3];
    float oy = Ai[4] * x + Ai[5] * y + Ai[6]  * z + Ai[7];
    float oz = Ai[8] * x + Ai[9] * y + Ai[10] * z + Ai[11];

    size_t po = ((size_t)b * N + n) * 3;
    out_pred[po + 0] = ox;
    out_pred[po + 1] = oy;
    out_pred[po + 2] = oz;

    size_t fo = (size_t)b * 3 * N + n;
    out_flow[fo]         = fx;
    out_flow[fo + N]     = fy;
    out_flow[fo + 2 * N] = fz;
}

extern "C" void kernel_launch(void* const* d_in, const int* in_sizes, int n_in,
                              void* d_out, int out_size, void* d_ws, size_t ws_size,
                              hipStream_t stream) {
    const float* verts  = (const float*)d_in[0];
    const float* affine = (const float*)d_in[1];
    const float* flow   = (const float*)d_in[2];

    int B = in_sizes[1] / 16;          // affine is B*4*4
    int N = in_sizes[0] / (3 * B);     // verts is B*N*3

    float* invaff   = (float*)d_ws;    // B*16 floats of scratch
    float* out_pred = (float*)d_out;                      // (B,N,3)
    float* out_flow = out_pred + (size_t)B * N * 3;       // (B,3,N)

    hipLaunchKernelGGL(invert4x4_kernel, dim3(1), dim3(64), 0, stream,
                       affine, invaff, B);

    int total = B * N;
    int block = 256;
    int grid = (total + block - 1) / block;
    hipLaunchKernelGGL(deform_kernel, dim3(grid), dim3(block), 0, stream,
                       verts, affine, flow, invaff, out_pred, out_flow, N, B);
}

// Round 2
// 316.591 us; speedup vs baseline: 1.0465x; 1.0465x over previous
//
#include <hip/hip_runtime.h>

#define NSTEPS 30
#define DIM 192
static constexpr int DHW = DIM * DIM * DIM;
static constexpr int PTS_PER_WAVE = 21;   // 3 lanes per point, lane 63 idle

// Unrolled cofactor 4x4 inverse in double — no dynamic indexing, no scratch.
__global__ void invert4x4_kernel(const float* __restrict__ aff,
                                 float* __restrict__ out, int B) {
    int b = blockIdx.x * blockDim.x + threadIdx.x;
    if (b >= B) return;
    double a[16];
#pragma unroll
    for (int i = 0; i < 16; i++) a[i] = (double)aff[b * 16 + i];

    double s0 = a[0]*a[5]  - a[4]*a[1];
    double s1 = a[0]*a[6]  - a[4]*a[2];
    double s2 = a[0]*a[7]  - a[4]*a[3];
    double s3 = a[1]*a[6]  - a[5]*a[2];
    double s4 = a[1]*a[7]  - a[5]*a[3];
    double s5 = a[2]*a[7]  - a[6]*a[3];
    double c5 = a[10]*a[15] - a[14]*a[11];
    double c4 = a[9]*a[15]  - a[13]*a[11];
    double c3 = a[9]*a[14]  - a[13]*a[10];
    double c2 = a[8]*a[15]  - a[12]*a[11];
    double c1 = a[8]*a[14]  - a[12]*a[10];
    double c0 = a[8]*a[13]  - a[12]*a[9];
    double det = s0*c5 - s1*c4 + s2*c3 + s3*c2 - s4*c1 + s5*c0;
    double inv = 1.0 / det;

    double o[16];
    o[0]  = ( a[5]*c5 - a[6]*c4 + a[7]*c3) * inv;
    o[1]  = (-a[1]*c5 + a[2]*c4 - a[3]*c3) * inv;
    o[2]  = ( a[13]*s5 - a[14]*s4 + a[15]*s3) * inv;
    o[3]  = (-a[9]*s5 + a[10]*s4 - a[11]*s3) * inv;
    o[4]  = (-a[4]*c5 + a[6]*c2 - a[7]*c1) * inv;
    o[5]  = ( a[0]*c5 - a[2]*c2 + a[3]*c1) * inv;
    o[6]  = (-a[12]*s5 + a[14]*s2 - a[15]*s1) * inv;
    o[7]  = ( a[8]*s5 - a[10]*s2 + a[11]*s1) * inv;
    o[8]  = ( a[4]*c4 - a[5]*c2 + a[7]*c0) * inv;
    o[9]  = (-a[0]*c4 + a[1]*c2 - a[3]*c0) * inv;
    o[10] = ( a[12]*s4 - a[13]*s2 + a[15]*s0) * inv;
    o[11] = (-a[8]*s4 + a[9]*s2 - a[11]*s0) * inv;
    o[12] = (-a[4]*c3 + a[5]*c1 - a[6]*c0) * inv;
    o[13] = ( a[0]*c3 - a[1]*c1 + a[2]*c0) * inv;
    o[14] = (-a[12]*s3 + a[13]*s1 - a[14]*s0) * inv;
    o[15] = ( a[8]*s3 - a[9]*s1 + a[10]*s0) * inv;
#pragma unroll
    for (int i = 0; i < 16; i++) out[b * 16 + i] = (float)o[i];
}

// 3 lanes per point: lane handles one flow channel (8-corner gather + lerp),
// position update exchanged via __shfl within the 3-lane group.
__global__ __launch_bounds__(256) void deform_kernel(
    const float* __restrict__ verts,
    const float* __restrict__ affine,
    const float* __restrict__ flow,
    const float* __restrict__ invaff,
    float* __restrict__ out_pred,
    float* __restrict__ out_flow,
    int N, int B) {
    int lane = threadIdx.x & 63;
    int wib  = threadIdx.x >> 6;
    long gwave = (long)blockIdx.x * (blockDim.x >> 6) + wib;

    int piw = lane / 3;                  // point-in-wave, 0..21
    if (piw > PTS_PER_WAVE - 1) piw = PTS_PER_WAVE - 1;
    int ch = lane - piw * 3;             // channel 0..2 (lane63 -> 3)
    if (ch > 2) ch = 2;

    long pt = gwave * PTS_PER_WAVE + piw;
    bool valid = (lane < 63) && (pt < (long)B * N);
    long ptc = valid ? pt : ((long)B * N - 1);
    int b = (int)(ptc / N);
    int n = (int)(ptc - (long)b * N);

    // affine transform: pred0 = A[0:3,:] @ [v,1]  (all 3 lanes track x,y,z)
    const float* A = affine + b * 16;
    const float* v = verts + (size_t)ptc * 3;
    float vx = v[0], vy = v[1], vz = v[2];
    float x = A[0] * vx + A[1] * vy + A[2]  * vz + A[3];
    float y = A[4] * vx + A[5] * vy + A[6]  * vz + A[7];
    float z = A[8] * vx + A[9] * vy + A[10] * vz + A[11];
    float p0 = (ch == 0) ? x : (ch == 1) ? y : z;   // own-channel initial pos

    const float* Fc = flow + ((size_t)b * 3 + ch) * (size_t)DHW;
    const float scale = (float)(1.0 / NSTEPS);  // matches jnp flow * (1/num_steps)

    float cc[8];      // cached (pre-scaled) corners of own channel
    int key = -1;
    int bl = piw * 3; // shuffle base lane of this point's 3-lane group

    for (int s = 0; s < NSTEPS; s++) {
        float pd = fminf(fmaxf(x, 0.0f), (float)(DIM - 1));
        float ph = fminf(fmaxf(y, 0.0f), (float)(DIM - 1));
        float pw = fminf(fmaxf(z, 0.0f), (float)(DIM - 1));
        float fd0 = floorf(pd), fh0 = floorf(ph), fw0 = floorf(pw);
        int d0 = (int)fd0, h0 = (int)fh0, w0 = (int)fw0;
        float fd = pd - fd0, fh = ph - fh0, fw = pw - fw0;

        int k = (d0 * DIM + h0) * DIM + w0;
        if (k != key) {
            key = k;
            int d1 = min(d0 + 1, DIM - 1);
            int h1 = min(h0 + 1, DIM - 1);
            int w1 = min(w0 + 1, DIM - 1);
            int r00 = (d0 * DIM + h0) * DIM;
            int r01 = (d0 * DIM + h1) * DIM;
            int r10 = (d1 * DIM + h0) * DIM;
            int r11 = (d1 * DIM + h1) * DIM;
            cc[0] = Fc[r00 + w0] * scale;
            cc[1] = Fc[r00 + w1] * scale;
            cc[2] = Fc[r01 + w0] * scale;
            cc[3] = Fc[r01 + w1] * scale;
            cc[4] = Fc[r10 + w0] * scale;
            cc[5] = Fc[r10 + w1] * scale;
            cc[6] = Fc[r11 + w0] * scale;
            cc[7] = Fc[r11 + w1] * scale;
        }

        float omfw = 1.0f - fw, omfh = 1.0f - fh, omfd = 1.0f - fd;
        float c00 = cc[0] * omfw + cc[1] * fw;
        float c01 = cc[2] * omfw + cc[3] * fw;
        float c10 = cc[4] * omfw + cc[5] * fw;
        float c11 = cc[6] * omfw + cc[7] * fw;
        float c0 = c00 * omfh + c01 * fh;
        float c1 = c10 * omfh + c11 * fh;
        float val = c0 * omfd + c1 * fd;

        // exchange the 3 channel values within the point's lane group
        float v0 = __shfl(val, bl,     64);
        float v1 = __shfl(val, bl + 1, 64);
        float v2 = __shfl(val, bl + 2, 64);
        x += v0; y += v1; z += v2;
    }

    if (valid) {
        // flow_int component for own channel, laid out (B,3,N)
        float posc = (ch == 0) ? x : (ch == 1) ? y : z;
        float fint = posc - p0;
        // inverse affine: own row only
        const float* Ai = invaff + b * 16 + ch * 4;
        float o = Ai[0] * x + Ai[1] * y + Ai[2] * z + Ai[3];
        out_pred[(size_t)ptc * 3 + ch] = o;                      // (B,N,3)
        out_flow[(size_t)b * 3 * N + (size_t)ch * N + n] = fint; // (B,3,N)
    }
}

extern "C" void kernel_launch(void* const* d_in, const int* in_sizes, int n_in,
                              void* d_out, int out_size, void* d_ws, size_t ws_size,
                              hipStream_t stream) {
    const float* verts  = (const float*)d_in[0];
    const float* affine = (const float*)d_in[1];
    const float* flow   = (const float*)d_in[2];

    int B = in_sizes[1] / 16;          // affine is B*4*4
    int N = in_sizes[0] / (3 * B);     // verts is B*N*3

    float* invaff   = (float*)d_ws;    // B*16 floats of scratch
    float* out_pred = (float*)d_out;                      // (B,N,3)
    float* out_flow = out_pred + (size_t)B * N * 3;       // (B,3,N)

    hipLaunchKernelGGL(invert4x4_kernel, dim3(1), dim3(64), 0, stream,
                       affine, invaff, B);

    long total_pts = (long)B * N;
    long waves  = (total_pts + PTS_PER_WAVE - 1) / PTS_PER_WAVE;
    long blocks = (waves + 3) / 4;     // 4 waves per 256-thread block
    hipLaunchKernelGGL(deform_kernel, dim3((unsigned)blocks), dim3(256), 0, stream,
                       verts, affine, flow, invaff, out_pred, out_flow, N, B);
}

// Round 3
// 306.093 us; speedup vs baseline: 1.0824x; 1.0343x over previous
//
#include <hip/hip_runtime.h>
#include <hip/hip_fp16.h>

#define NSTEPS 30
#define DIM 192
static constexpr long DHW = (long)DIM * DIM * DIM;
static constexpr int PTS_PER_WAVE = 21;   // 3 lanes per point, lane 63 idle

// Unrolled cofactor 4x4 inverse in double — registers only, no scratch.
__global__ void invert4x4_kernel(const float* __restrict__ aff,
                                 float* __restrict__ out, int B) {
    int b = blockIdx.x * blockDim.x + threadIdx.x;
    if (b >= B) return;
    double a[16];
#pragma unroll
    for (int i = 0; i < 16; i++) a[i] = (double)aff[b * 16 + i];
    double s0 = a[0]*a[5]  - a[4]*a[1];
    double s1 = a[0]*a[6]  - a[4]*a[2];
    double s2 = a[0]*a[7]  - a[4]*a[3];
    double s3 = a[1]*a[6]  - a[5]*a[2];
    double s4 = a[1]*a[7]  - a[5]*a[3];
    double s5 = a[2]*a[7]  - a[6]*a[3];
    double c5 = a[10]*a[15] - a[14]*a[11];
    double c4 = a[9]*a[15]  - a[13]*a[11];
    double c3 = a[9]*a[14]  - a[13]*a[10];
    double c2 = a[8]*a[15]  - a[12]*a[11];
    double c1 = a[8]*a[14]  - a[12]*a[10];
    double c0 = a[8]*a[13]  - a[12]*a[9];
    double det = s0*c5 - s1*c4 + s2*c3 + s3*c2 - s4*c1 + s5*c0;
    double inv = 1.0 / det;
    double o[16];
    o[0]  = ( a[5]*c5 - a[6]*c4 + a[7]*c3) * inv;
    o[1]  = (-a[1]*c5 + a[2]*c4 - a[3]*c3) * inv;
    o[2]  = ( a[13]*s5 - a[14]*s4 + a[15]*s3) * inv;
    o[3]  = (-a[9]*s5 + a[10]*s4 - a[11]*s3) * inv;
    o[4]  = (-a[4]*c5 + a[6]*c2 - a[7]*c1) * inv;
    o[5]  = ( a[0]*c5 - a[2]*c2 + a[3]*c1) * inv;
    o[6]  = (-a[12]*s5 + a[14]*s2 - a[15]*s1) * inv;
    o[7]  = ( a[8]*s5 - a[10]*s2 + a[11]*s1) * inv;
    o[8]  = ( a[4]*c4 - a[5]*c2 + a[7]*c0) * inv;
    o[9]  = (-a[0]*c4 + a[1]*c2 - a[3]*c0) * inv;
    o[10] = ( a[12]*s4 - a[13]*s2 + a[15]*s0) * inv;
    o[11] = (-a[8]*s4 + a[9]*s2 - a[11]*s0) * inv;
    o[12] = (-a[4]*c3 + a[5]*c1 - a[6]*c0) * inv;
    o[13] = ( a[0]*c3 - a[1]*c1 + a[2]*c0) * inv;
    o[14] = (-a[12]*s3 + a[13]*s1 - a[14]*s0) * inv;
    o[15] = ( a[8]*s3 - a[9]*s1 + a[10]*s0) * inv;
#pragma unroll
    for (int i = 0; i < 16; i++) out[b * 16 + i] = (float)o[i];
}

// Repack flow (B,3,D,H,W) f32 -> (B,D,H,W,4) fp16 (channel-interleaved, 8B/voxel)
__global__ __launch_bounds__(256) void repack_kernel(const float* __restrict__ flow,
                                                     __half* __restrict__ packed) {
    long vox = (long)blockIdx.x * blockDim.x + threadIdx.x;
    int b = blockIdx.y;
    if (vox >= DHW) return;
    const float* F = flow + (size_t)b * 3 * DHW;
    float f0 = F[vox];
    float f1 = F[vox + DHW];
    float f2 = F[vox + 2 * DHW];
    union { __half2 h2[2]; int2 i2; } u;
    u.h2[0] = __floats2half2_rn(f0, f1);
    u.h2[1] = __floats2half2_rn(f2, 0.0f);
    reinterpret_cast<int2*>(packed)[(size_t)b * DHW + vox] = u.i2;
}

// 3 lanes per point, gathering from the interleaved fp16 volume.
__global__ __launch_bounds__(256) void deform_packed_kernel(
    const float* __restrict__ verts,
    const float* __restrict__ affine,
    const __half* __restrict__ packed,
    const float* __restrict__ invaff,
    float* __restrict__ out_pred,
    float* __restrict__ out_flow,
    int N, int B) {
    int lane = threadIdx.x & 63;
    int wib  = threadIdx.x >> 6;
    long gwave = (long)blockIdx.x * (blockDim.x >> 6) + wib;

    int piw = lane / 3;
    if (piw > PTS_PER_WAVE - 1) piw = PTS_PER_WAVE - 1;
    int ch = lane - piw * 3;
    if (ch > 2) ch = 2;

    long pt = gwave * PTS_PER_WAVE + piw;
    bool valid = (lane < 63) && (pt < (long)B * N);
    long ptc = valid ? pt : ((long)B * N - 1);
    int b = (int)(ptc / N);
    int n = (int)(ptc - (long)b * N);

    const float* A = affine + b * 16;
    const float* v = verts + (size_t)ptc * 3;
    float vx = v[0], vy = v[1], vz = v[2];
    float x = A[0] * vx + A[1] * vy + A[2]  * vz + A[3];
    float y = A[4] * vx + A[5] * vy + A[6]  * vz + A[7];
    float z = A[8] * vx + A[9] * vy + A[10] * vz + A[11];
    float p0 = (ch == 0) ? x : (ch == 1) ? y : z;

    // own-channel base into the interleaved volume (units: halves)
    const __half* Pb = packed + ((size_t)b * DHW) * 4 + ch;
    const float scale = (float)(1.0 / NSTEPS);

    float cc[8];
    int key = -1;
    int bl = piw * 3;

    for (int s = 0; s < NSTEPS; s++) {
        float pd = fminf(fmaxf(x, 0.0f), (float)(DIM - 1));
        float ph = fminf(fmaxf(y, 0.0f), (float)(DIM - 1));
        float pw = fminf(fmaxf(z, 0.0f), (float)(DIM - 1));
        float fd0 = floorf(pd), fh0 = floorf(ph), fw0 = floorf(pw);
        int d0 = (int)fd0, h0 = (int)fh0, w0 = (int)fw0;
        float fd = pd - fd0, fh = ph - fh0, fw = pw - fw0;

        int k = (d0 * DIM + h0) * DIM + w0;
        if (k != key) {
            key = k;
            int d1 = min(d0 + 1, DIM - 1);
            int h1 = min(h0 + 1, DIM - 1);
            int w1 = min(w0 + 1, DIM - 1);
            size_t r00 = (size_t)((d0 * DIM + h0) * DIM) * 4;
            size_t r01 = (size_t)((d0 * DIM + h1) * DIM) * 4;
            size_t r10 = (size_t)((d1 * DIM + h0) * DIM) * 4;
            size_t r11 = (size_t)((d1 * DIM + h1) * DIM) * 4;
            size_t o0 = (size_t)w0 * 4, o1 = (size_t)w1 * 4;
            cc[0] = __half2float(Pb[r00 + o0]) * scale;
            cc[1] = __half2float(Pb[r00 + o1]) * scale;
            cc[2] = __half2float(Pb[r01 + o0]) * scale;
            cc[3] = __half2float(Pb[r01 + o1]) * scale;
            cc[4] = __half2float(Pb[r10 + o0]) * scale;
            cc[5] = __half2float(Pb[r10 + o1]) * scale;
            cc[6] = __half2float(Pb[r11 + o0]) * scale;
            cc[7] = __half2float(Pb[r11 + o1]) * scale;
        }

        float omfw = 1.0f - fw, omfh = 1.0f - fh, omfd = 1.0f - fd;
        float c00 = cc[0] * omfw + cc[1] * fw;
        float c01 = cc[2] * omfw + cc[3] * fw;
        float c10 = cc[4] * omfw + cc[5] * fw;
        float c11 = cc[6] * omfw + cc[7] * fw;
        float c0 = c00 * omfh + c01 * fh;
        float c1 = c10 * omfh + c11 * fh;
        float val = c0 * omfd + c1 * fd;

        float v0 = __shfl(val, bl,     64);
        float v1 = __shfl(val, bl + 1, 64);
        float v2 = __shfl(val, bl + 2, 64);
        x += v0; y += v1; z += v2;
    }

    if (valid) {
        float posc = (ch == 0) ? x : (ch == 1) ? y : z;
        float fint = posc - p0;
        const float* Ai = invaff + b * 16 + ch * 4;
        float o = Ai[0] * x + Ai[1] * y + Ai[2] * z + Ai[3];
        out_pred[(size_t)ptc * 3 + ch] = o;
        out_flow[(size_t)b * 3 * N + (size_t)ch * N + n] = fint;
    }
}

// Fallback: round-2 f32 direct-gather kernel (used only if ws too small).
__global__ __launch_bounds__(256) void deform_kernel(
    const float* __restrict__ verts,
    const float* __restrict__ affine,
    const float* __restrict__ flow,
    const float* __restrict__ invaff,
    float* __restrict__ out_pred,
    float* __restrict__ out_flow,
    int N, int B) {
    int lane = threadIdx.x & 63;
    int wib  = threadIdx.x >> 6;
    long gwave = (long)blockIdx.x * (blockDim.x >> 6) + wib;
    int piw = lane / 3;
    if (piw > PTS_PER_WAVE - 1) piw = PTS_PER_WAVE - 1;
    int ch = lane - piw * 3;
    if (ch > 2) ch = 2;
    long pt = gwave * PTS_PER_WAVE + piw;
    bool valid = (lane < 63) && (pt < (long)B * N);
    long ptc = valid ? pt : ((long)B * N - 1);
    int b = (int)(ptc / N);
    int n = (int)(ptc - (long)b * N);
    const float* A = affine + b * 16;
    const float* v = verts + (size_t)ptc * 3;
    float vx = v[0], vy = v[1], vz = v[2];
    float x = A[0] * vx + A[1] * vy + A[2]  * vz + A[3];
    float y = A[4] * vx + A[5] * vy + A[6]  * vz + A[7];
    float z = A[8] * vx + A[9] * vy + A[10] * vz + A[11];
    float p0 = (ch == 0) ? x : (ch == 1) ? y : z;
    const float* Fc = flow + ((size_t)b * 3 + ch) * (size_t)DHW;
    const float scale = (float)(1.0 / NSTEPS);
    float cc[8];
    int key = -1;
    int bl = piw * 3;
    for (int s = 0; s < NSTEPS; s++) {
        float pd = fminf(fmaxf(x, 0.0f), (float)(DIM - 1));
        float ph = fminf(fmaxf(y, 0.0f), (float)(DIM - 1));
        float pw = fminf(fmaxf(z, 0.0f), (float)(DIM - 1));
        float fd0 = floorf(pd), fh0 = floorf(ph), fw0 = floorf(pw);
        int d0 = (int)fd0, h0 = (int)fh0, w0 = (int)fw0;
        float fd = pd - fd0, fh = ph - fh0, fw = pw - fw0;
        int k = (d0 * DIM + h0) * DIM + w0;
        if (k != key) {
            key = k;
            int d1 = min(d0 + 1, DIM - 1);
            int h1 = min(h0 + 1, DIM - 1);
            int w1 = min(w0 + 1, DIM - 1);
            int r00 = (d0 * DIM + h0) * DIM;
            int r01 = (d0 * DIM + h1) * DIM;
            int r10 = (d1 * DIM + h0) * DIM;
            int r11 = (d1 * DIM + h1) * DIM;
            cc[0] = Fc[r00 + w0] * scale;
            cc[1] = Fc[r00 + w1] * scale;
            cc[2] = Fc[r01 + w0] * scale;
            cc[3] = Fc[r01 + w1] * scale;
            cc[4] = Fc[r10 + w0] * scale;
            cc[5] = Fc[r10 + w1] * scale;
            cc[6] = Fc[r11 + w0] * scale;
            cc[7] = Fc[r11 + w1] * scale;
        }
        float omfw = 1.0f - fw, omfh = 1.0f - fh, omfd = 1.0f - fd;
        float c00 = cc[0] * omfw + cc[1] * fw;
        float c01 = cc[2] * omfw + cc[3] * fw;
        float c10 = cc[4] * omfw + cc[5] * fw;
        float c11 = cc[6] * omfw + cc[7] * fw;
        float c0 = c00 * omfh + c01 * fh;
        float c1 = c10 * omfh + c11 * fh;
        float val = c0 * omfd + c1 * fd;
        float v0 = __shfl(val, bl,     64);
        float v1 = __shfl(val, bl + 1, 64);
        float v2 = __shfl(val, bl + 2, 64);
        x += v0; y += v1; z += v2;
    }
    if (valid) {
        float posc = (ch == 0) ? x : (ch == 1) ? y : z;
        float fint = posc - p0;
        const float* Ai = invaff + b * 16 + ch * 4;
        float o = Ai[0] * x + Ai[1] * y + Ai[2] * z + Ai[3];
        out_pred[(size_t)ptc * 3 + ch] = o;
        out_flow[(size_t)b * 3 * N + (size_t)ch * N + n] = fint;
    }
}

extern "C" void kernel_launch(void* const* d_in, const int* in_sizes, int n_in,
                              void* d_out, int out_size, void* d_ws, size_t ws_size,
                              hipStream_t stream) {
    const float* verts  = (const float*)d_in[0];
    const float* affine = (const float*)d_in[1];
    const float* flow   = (const float*)d_in[2];

    int B = in_sizes[1] / 16;          // affine is B*4*4
    int N = in_sizes[0] / (3 * B);     // verts is B*N*3

    float* out_pred = (float*)d_out;                      // (B,N,3)
    float* out_flow = out_pred + (size_t)B * N * 3;       // (B,3,N)

    size_t packed_bytes = (size_t)B * DHW * 4 * sizeof(__half);  // 8B/voxel
    bool use_packed = (ws_size >= packed_bytes + 256);

    long total_pts = (long)B * N;
    long waves  = (total_pts + PTS_PER_WAVE - 1) / PTS_PER_WAVE;
    long blocks = (waves + 3) / 4;     // 4 waves per 256-thread block

    if (use_packed) {
        __half* packed = (__half*)d_ws;
        float* invaff  = (float*)((char*)d_ws + packed_bytes);
        hipLaunchKernelGGL(invert4x4_kernel, dim3(1), dim3(64), 0, stream,
                           affine, invaff, B);
        long vblocks = (DHW + 255) / 256;
        hipLaunchKernelGGL(repack_kernel, dim3((unsigned)vblocks, B), dim3(256), 0,
                           stream, flow, packed);
        hipLaunchKernelGGL(deform_packed_kernel, dim3((unsigned)blocks), dim3(256),
                           0, stream, verts, affine, packed, invaff,
                           out_pred, out_flow, N, B);
    } else {
        float* invaff = (float*)d_ws;
        hipLaunchKernelGGL(invert4x4_kernel, dim3(1), dim3(64), 0, stream,
                           affine, invaff, B);
        hipLaunchKernelGGL(deform_kernel, dim3((unsigned)blocks), dim3(256), 0,
                           stream, verts, affine, flow, invaff,
                           out_pred, out_flow, N, B);
    }
}